// Round 4
// baseline (713.762 us; speedup 1.0000x reference)
//
#include <hip/hip_runtime.h>
#include <math.h>

#define D_MODEL 256
#define N_PATCH 196
#define NWAVES  4        // block = 256 threads
#define N_TILES 2048     // 32 * 64 (b,n) tiles — problem shape is fixed

typedef float v4f __attribute__((ext_vector_type(4)));

// One block per (b,n) tile. Single pass over h_p (411 MB read exactly once).
// Wave w owns patches p = w + 4k, k in [0,49). Groups of 4 patches, manual
// 2-deep software pipeline: group i+1's 8 loads are in flight while group i
// runs its shuffle-reduce + online-softmax update. h_p loads are nontemporal
// (streaming, zero reuse) so pe (read 2048x) stays L2-resident.
__global__ __launch_bounds__(256, 4) void qba_kernel(
    const float* __restrict__ h_p,     // [2048, 196, 256]
    const float* __restrict__ query,   // [256]
    const float* __restrict__ pe,      // [196, 256]
    float* __restrict__ out)           // [2048, 256]
{
    const int t    = threadIdx.x;
    const int lane = t & 63;
    const int w    = t >> 6;
    const int bn   = blockIdx.x;

    const v4f q4 = ((const v4f*)query)[lane];

    const v4f* __restrict__ hp4 = (const v4f*)(h_p + (size_t)bn * N_PATCH * D_MODEL);
    const v4f* __restrict__ pe4 = (const v4f*)pe;

    float m = -INFINITY;
    float l = 0.0f;
    v4f   o = {0.0f, 0.0f, 0.0f, 0.0f};

    v4f hb[2][4], eb[2][4];

#define LOAD_GROUP(i, B) do {                                   \
        const int base_ = (w + 16 * (i)) * 64 + lane;           \
        hb[B][0] = __builtin_nontemporal_load(&hp4[base_      ]); \
        hb[B][1] = __builtin_nontemporal_load(&hp4[base_ + 256]); \
        hb[B][2] = __builtin_nontemporal_load(&hp4[base_ + 512]); \
        hb[B][3] = __builtin_nontemporal_load(&hp4[base_ + 768]); \
        eb[B][0] = pe4[base_      ];                            \
        eb[B][1] = pe4[base_ + 256];                            \
        eb[B][2] = pe4[base_ + 512];                            \
        eb[B][3] = pe4[base_ + 768];                            \
    } while (0)

    // prologue: group 0 into buffer 0
    LOAD_GROUP(0, 0);

    #pragma unroll
    for (int i = 0; i < 12; ++i) {
        const int cur = i & 1;
        const int nxt = cur ^ 1;

        // issue next group's loads before touching current group's data
        if (i < 11) {
            LOAD_GROUP(i + 1, nxt);
        } else {
            // tail patch p = 192 + w into slot 0 of the other buffer
            const int base_ = (192 + w) * 64 + lane;
            hb[nxt][0] = __builtin_nontemporal_load(&hp4[base_]);
            eb[nxt][0] = pe4[base_];
        }

        v4f v0 = hb[cur][0] + eb[cur][0];
        v4f v1 = hb[cur][1] + eb[cur][1];
        v4f v2 = hb[cur][2] + eb[cur][2];
        v4f v3 = hb[cur][3] + eb[cur][3];

        float d0 = v0.x * q4.x + v0.y * q4.y + v0.z * q4.z + v0.w * q4.w;
        float d1 = v1.x * q4.x + v1.y * q4.y + v1.z * q4.z + v1.w * q4.w;
        float d2 = v2.x * q4.x + v2.y * q4.y + v2.z * q4.z + v2.w * q4.w;
        float d3 = v3.x * q4.x + v3.y * q4.y + v3.z * q4.z + v3.w * q4.w;

        #pragma unroll
        for (int off = 32; off > 0; off >>= 1) {
            d0 += __shfl_xor(d0, off, 64);
            d1 += __shfl_xor(d1, off, 64);
            d2 += __shfl_xor(d2, off, 64);
            d3 += __shfl_xor(d3, off, 64);
        }

        const float s0 = d0 * 0.0625f;
        const float s1 = d1 * 0.0625f;
        const float s2 = d2 * 0.0625f;
        const float s3 = d3 * 0.0625f;

        const float m_new = fmaxf(fmaxf(fmaxf(m, s0), fmaxf(s1, s2)), s3);
        const float alpha = __expf(m - m_new);      // exp(-inf)=0 on first iter
        const float w0 = __expf(s0 - m_new);
        const float w1 = __expf(s1 - m_new);
        const float w2 = __expf(s2 - m_new);
        const float w3 = __expf(s3 - m_new);
        l = l * alpha + (w0 + w1 + w2 + w3);
        o.x = o.x * alpha + w0 * v0.x + w1 * v1.x + w2 * v2.x + w3 * v3.x;
        o.y = o.y * alpha + w0 * v0.y + w1 * v1.y + w2 * v2.y + w3 * v3.y;
        o.z = o.z * alpha + w0 * v0.z + w1 * v1.z + w2 * v2.z + w3 * v3.z;
        o.w = o.w * alpha + w0 * v0.w + w1 * v1.w + w2 * v2.w + w3 * v3.w;
        m = m_new;
    }
#undef LOAD_GROUP

    // ---- tail: p = 192 + w, sitting in buffer 0 slot 0 (12 & 1 == 0) ----
    {
        v4f v = hb[0][0] + eb[0][0];
        float d = v.x * q4.x + v.y * q4.y + v.z * q4.z + v.w * q4.w;
        #pragma unroll
        for (int off = 32; off > 0; off >>= 1)
            d += __shfl_xor(d, off, 64);

        const float s = d * 0.0625f;
        const float m_new = fmaxf(m, s);
        const float alpha = __expf(m - m_new);
        const float wp    = __expf(s - m_new);
        l   = l * alpha + wp;
        o.x = o.x * alpha + wp * v.x;
        o.y = o.y * alpha + wp * v.y;
        o.z = o.z * alpha + wp * v.z;
        o.w = o.w * alpha + wp * v.w;
        m = m_new;
    }

    // ---- merge the 4 per-wave states ----
    __shared__ float sm[NWAVES];
    __shared__ float sl[NWAVES];
    __shared__ float so[NWAVES][D_MODEL];

    if (lane == 0) { sm[w] = m; sl[w] = l; }
    *((v4f*)&so[w][lane * 4]) = o;
    __syncthreads();

    const float M  = fmaxf(fmaxf(sm[0], sm[1]), fmaxf(sm[2], sm[3]));
    const float e0 = __expf(sm[0] - M);
    const float e1 = __expf(sm[1] - M);
    const float e2 = __expf(sm[2] - M);
    const float e3 = __expf(sm[3] - M);
    const float L  = sl[0] * e0 + sl[1] * e1 + sl[2] * e2 + sl[3] * e3;

    const float num = so[0][t] * e0 + so[1][t] * e1 + so[2][t] * e2 + so[3][t] * e3;
    out[(size_t)bn * D_MODEL + t] = num / L;
}

extern "C" void kernel_launch(void* const* d_in, const int* in_sizes, int n_in,
                              void* d_out, int out_size, void* d_ws, size_t ws_size,
                              hipStream_t stream) {
    (void)in_sizes; (void)n_in; (void)d_ws; (void)ws_size; (void)out_size;
    const float* h_p   = (const float*)d_in[0];  // [32,64,196,256]
    const float* query = (const float*)d_in[1];  // [1,1,256]
    const float* pe    = (const float*)d_in[2];  // [1,196,256]
    float* out = (float*)d_out;                  // [32,64,256]

    qba_kernel<<<N_TILES, 256, 0, stream>>>(h_p, query, pe, out);
}